// Round 1
// baseline (141.089 us; speedup 1.0000x reference)
//
#include <hip/hip_runtime.h>
#include <stdint.h>

// monotone order-preserving float<->uint mapping (works for all signs)
__device__ __forceinline__ uint32_t mapf(float f) {
  uint32_t u = __float_as_uint(f);
  return (u & 0x80000000u) ? ~u : (u | 0x80000000u);
}
__device__ __forceinline__ float unmapf(uint32_t m) {
  return (m & 0x80000000u) ? __uint_as_float(m & 0x7FFFFFFFu) : __uint_as_float(~m);
}

// ws dwords: [8..39]=table: 8 x (rlo,rhi,scale,offset)
//            [64..79]=slotA (mapped max, 16-way spread)  [80..95]=slotB (mapped -min)

// ---------------- kernel 1: global min/max (spread atomics),
//                  block 0 also builds byte table + copies small outputs ----------------
__global__ __launch_bounds__(256) void k_minmax(const float* __restrict__ x, int n4, int ntail,
                                                const float* __restrict__ co, const float* __restrict__ sfil,
                                                uint32_t* __restrict__ wsu,
                                                float* __restrict__ out_co, float* __restrict__ out_sf) {
  __shared__ float smn[256], smx[256];
  int tid = threadIdx.x;
  float mn = 3.0e38f, mx = -3.0e38f;
  const float4* x4 = (const float4*)x;
  int stride = gridDim.x * blockDim.x;
  #pragma unroll 4
  for (int i = blockIdx.x * blockDim.x + tid; i < n4; i += stride) {
    float4 v = x4[i];
    mn = fminf(mn, fminf(fminf(v.x, v.y), fminf(v.z, v.w)));
    mx = fmaxf(mx, fmaxf(fmaxf(v.x, v.y), fmaxf(v.z, v.w)));
  }
  if (blockIdx.x == 0 && tid == 0) {
    for (int i = 4 * n4; i < 4 * n4 + ntail; ++i) { mn = fminf(mn, x[i]); mx = fmaxf(mx, x[i]); }
  }
  smn[tid] = mn; smx[tid] = mx;
  __syncthreads();
  for (int s = 128; s > 0; s >>= 1) {
    if (tid < s) { smn[tid] = fminf(smn[tid], smn[tid + s]); smx[tid] = fmaxf(smx[tid], smx[tid + s]); }
    __syncthreads();
  }
  if (tid == 0) {
    int slot = blockIdx.x & 15;
    atomicMax(&wsu[64 + slot], mapf(smx[0]));    // max
    atomicMax(&wsu[80 + slot], mapf(-smn[0]));   // min via max of negation (exact)
  }
  if (blockIdx.x == 0) {
    if (tid < 8) {   // per-row byte quantization of co_matrix
      const float* r = co + tid * 8;
      float rmn = r[0], rmx = r[0];
      #pragma unroll
      for (int j = 1; j < 8; ++j) { rmn = fminf(rmn, r[j]); rmx = fmaxf(rmx, r[j]); }
      float rs = (rmx - rmn) * (1.0f / 255.0f);
      if (rs < 1e-30f) rs = 1.0f;
      uint32_t d0 = 0, d1 = 0;
      #pragma unroll
      for (int j = 0; j < 8; ++j) {
        int b = (int)lrintf((r[j] - rmn) / rs);
        b = b < 0 ? 0 : (b > 255 ? 255 : b);
        if (j < 4) d0 |= ((uint32_t)b) << (8 * j);
        else       d1 |= ((uint32_t)b) << (8 * (j - 4));
      }
      wsu[8 + 4 * tid + 0] = d0;
      wsu[8 + 4 * tid + 1] = d1;
      wsu[8 + 4 * tid + 2] = __float_as_uint(rs);
      wsu[8 + 4 * tid + 3] = __float_as_uint(rmn);
    }
    if (tid < 64) out_co[tid] = co[tid];
    if (tid < 27) out_sf[tid] = sfil[tid];
  }
}

// 5-op scaled Markstein: d8 = 8 * RN((xv-mn)/mx), bit-exact.
// y8 = 8*RN(1/mx), mx8 = mx/8 (both exact pow2 scalings; RN commutes with *8).
__device__ __forceinline__ float quant_d8(float xv, float mn, float mx8, float y8) {
  float s   = xv - mn;
  float t08 = s * y8;
  float r0  = __builtin_fmaf(-mx8, t08, s);
  return __builtin_fmaf(r0, y8, t08);
}

// ---------------- kernel 2: fused quantize + selected 27-tap stencil ----------------
// tile: 2 c x 8 h x 128 w; 256 threads = 32(w) x 8(h); 4 w-outputs/thread, 2 c-iters
// xs uses a conflict-free stride-5 group layout: logical element L lives at
// phys = 5*(L>>2) + (L&3); row stride = 165 dwords (== 5 mod 32).
// All window reads {5tw..5tw+3, 5tw+5, 5tw+6} hit 32 distinct banks (5 coprime 32);
// cross-row (ty) overlap is 2-way == free. LDS 31.8 KB -> 5 blocks/CU.
__global__ __launch_bounds__(256) void k_conv(const float* __restrict__ x, const float* __restrict__ sfil,
                                              const uint32_t* __restrict__ wsu,
                                              float* __restrict__ out, float* __restrict__ out_idx) {
  __shared__ __align__(16) float    xs[6600];    // 40 rows x 165 (32 groups*5 + tail group + pad)
  __shared__ __align__(16) uint32_t qls[1320];   // 40 x 33 (4 clamped q-bytes per dword)
  __shared__ __align__(16) uint4    tbl[8];      // rlo, rhi, scale, offset per q0

  int tid = threadIdx.x;
  int b = blockIdx.x;
  int wt = b & 1, ht = (b >> 1) & 31, ct = (b >> 6) & 7, n = b >> 9;
  int c0 = ct * 2, h0 = ht * 8, w0 = wt * 128;
  int nbase = n * 16;

  if (tid < 8) tbl[tid] = ((const uint4*)(wsu + 8))[tid];

  // reduce the 16+16 spread slots (uniform scalar loads)
  uint32_t ma = 0u, mb = 0u;
  #pragma unroll
  for (int i = 0; i < 16; ++i) {
    uint32_t a = wsu[64 + i], bq = wsu[80 + i];
    ma = ma > a ? ma : a;
    mb = mb > bq ? mb : bq;
  }
  float mx = unmapf(ma);
  float mn = -unmapf(mb);
  float y   = 1.0f / mx;     // correctly-rounded IEEE reciprocal
  float y8  = y * 8.0f;      // exact
  float mx8 = mx * 0.125f;   // exact

  const int tx = tid & 31, ty = tid >> 5;

  // ---- staging: 40 rows x 32 groups (division-free) + 40-group tail column ----
  {
    const int xoff = 5 * tx;               // stride-5 group base within row
    #pragma unroll
    for (int it = 0; it < 5; ++it) {
      int rr = ty + 8 * it;                // 0..39
      int lc = (rr * 13) >> 7;             // rr/10 for rr<40
      int lh = rr - 10 * lc;
      int c = c0 - 1 + lc, h = h0 - 1 + lh;
      bool chok = ((unsigned)c < 16u) & ((unsigned)h < 256u);
      int chbase = ((nbase + c) << 16) + (h << 8);
      int wq = w0 + 4 * tx;                // <=252 always: quad load never OOB in w
      float4 vb = float4{0.f, 0.f, 0.f, 0.f};
      if (chok) vb = *(const float4*)&x[chbase + wq];
      float pe = __shfl_up(vb.w, 1);       // prev group's quad.w == x[wq-1]
      if (tx == 0) {
        int wm = wq - 1;
        pe = (chok & (wm >= 0)) ? x[chbase + wm] : 0.0f;
      }
      float xv[4] = {pe, vb.x, vb.y, vb.z};
      uint32_t qu[4];
      #pragma unroll
      for (int j = 0; j < 4; ++j) {
        int q = (int)quant_d8(xv[j], mn, mx8, y8);
        qu[j] = min((uint32_t)q, 7u);      // JAX gather clamps OOB index for tap lookups
      }
      uint32_t b01 = __builtin_amdgcn_perm(qu[1], qu[0], 0x0c0c0400u);
      uint32_t b23 = __builtin_amdgcn_perm(qu[3], qu[2], 0x04000c0cu);
      int xb = rr * 165 + xoff;
      xs[xb + 0] = xv[0];
      xs[xb + 1] = xv[1];
      xs[xb + 2] = xv[2];
      xs[xb + 3] = xv[3];
      qls[rr * 33 + tx] = b01 | b23;
    }
    if (tid < 40) {                        // tail: lg = 32 for each of the 40 rows
      int rr = tid;
      int lc = (rr * 13) >> 7;
      int lh = rr - 10 * lc;
      int c = c0 - 1 + lc, h = h0 - 1 + lh;
      bool chok = ((unsigned)c < 16u) & ((unsigned)h < 256u);
      int chbase = ((nbase + c) << 16) + (h << 8);
      int wq = w0 + 128;                   // may be 256 (OOB) when w0==128
      float4 vb = float4{0.f, 0.f, 0.f, 0.f};
      if (chok & (wq < 256)) vb = *(const float4*)&x[chbase + wq];
      float pe = chok ? x[chbase + wq - 1] : 0.0f;   // wq-1 <= 255 always
      float xv[4] = {pe, vb.x, vb.y, vb.z};
      uint32_t qu[4];
      #pragma unroll
      for (int j = 0; j < 4; ++j) {
        int q = (int)quant_d8(xv[j], mn, mx8, y8);
        qu[j] = min((uint32_t)q, 7u);
      }
      uint32_t b01 = __builtin_amdgcn_perm(qu[1], qu[0], 0x0c0c0400u);
      uint32_t b23 = __builtin_amdgcn_perm(qu[3], qu[2], 0x04000c0cu);
      int xb = rr * 165 + 160;             // group 32 -> phys 160..163
      xs[xb + 0] = xv[0];
      xs[xb + 1] = xv[1];
      xs[xb + 2] = xv[2];
      xs[xb + 3] = xv[3];
      qls[rr * 33 + 32] = b01 | b23;
    }
  }
  __syncthreads();

  float wf[27];
  #pragma unroll
  for (int i = 0; i < 27; ++i) wf[i] = sfil[i];   // uniform -> scalar regs

  const int tw = tx, th = ty;
  const uint32_t SELK[4] = {0x03020100u, 0x04030201u, 0x05040302u, 0x06050403u};

  for (int c = 0; c < 2; ++c) {
    int xbase = (c * 10 + th) * 165 + 5 * tw;
    int qbase = (c * 10 + th) * 33 + tw;

    // center q-bytes (clamped) -> per-output table rows
    int qc = qbase + 11 * 33;
    uint32_t Qc0 = qls[qc], Qc1 = qls[qc + 1];
    uint32_t q4 = __builtin_amdgcn_perm(Qc1, Qc0, 0x04030201u);
    uint32_t rlo[4], rhi[4]; float rs4[4], rc4[4];
    #pragma unroll
    for (int k = 0; k < 4; ++k) {
      uint32_t qk = (q4 >> (8 * k)) & 0xffu;
      uint4 T = tbl[qk];
      rlo[k] = T.x; rhi[k] = T.y;
      rs4[k] = __uint_as_float(T.z); rc4[k] = __uint_as_float(T.w);
    }

    float acc1[4] = {0.f, 0.f, 0.f, 0.f};
    float acc2[4] = {0.f, 0.f, 0.f, 0.f};
    float cc0, cc1, cc2, cc3;   // center-row clean x (captured at dc=1,di=1)
    #pragma unroll
    for (int dc = 0; dc < 3; ++dc) {
      #pragma unroll
      for (int di = 0; di < 3; ++di) {
        int xo = xbase + (dc * 10 + di) * 165;
        // conflict-free window read: 6 dwords, all-distinct banks across the wave
        float a0 = xs[xo + 0];
        float a1 = xs[xo + 1];
        float a2 = xs[xo + 2];
        float a3 = xs[xo + 3];
        float a4 = xs[xo + 5];   // group tw+1, elem 0
        float a5 = xs[xo + 6];   // group tw+1, elem 1
        if (dc == 1 && di == 1) { cc0 = a1; cc1 = a2; cc2 = a3; cc3 = a4; }
        int qo = qbase + (dc * 10 + di) * 33;
        uint32_t Q0 = qls[qo], Q1 = qls[qo + 1];
        float xw[6] = {a0, a1, a2, a3, a4, a5};
        const float* wr = &wf[dc * 9 + di * 3];
        #pragma unroll
        for (int k = 0; k < 4; ++k) {
          uint32_t sel = __builtin_amdgcn_perm(Q1, Q0, SELK[k]);     // 3 q-bytes
          uint32_t bb  = __builtin_amdgcn_perm(rhi[k], rlo[k], sel); // 3 table bytes
          float b0 = (float)(bb & 0xffu);          // v_cvt_f32_ubyte0
          float b1 = (float)((bb >> 8) & 0xffu);   // v_cvt_f32_ubyte1
          float b2 = (float)((bb >> 16) & 0xffu);  // v_cvt_f32_ubyte2
          float p0 = wr[0] * xw[k];
          float p1 = wr[1] * xw[k + 1];
          float p2 = wr[2] * xw[k + 2];
          acc2[k] += p0 + p1 + p2;
          acc1[k] = __builtin_fmaf(p0, b0, acc1[k]);
          acc1[k] = __builtin_fmaf(p1, b1, acc1[k]);
          acc1[k] = __builtin_fmaf(p2, b2, acc1[k]);
        }
      }
    }

    // epilogue: d8 per center element; idx = trunc(d8) (8.0 falls out naturally)
    float cx[4] = {cc0, cc1, cc2, cc3};
    float idxf[4]; float vals[4];
    #pragma unroll
    for (int k = 0; k < 4; ++k) {
      float d8 = quant_d8(cx[k], mn, mx8, y8);
      idxf[k] = truncf(d8);
      float v = __builtin_fmaf(rs4[k], acc1[k], rc4[k] * acc2[k]);
      vals[k] = (d8 >= 8.0f) ? 0.0f : v;   // idx==8 matches no mask channel
    }

    int gbase = ((nbase + c0 + c) << 16) + ((h0 + th) << 8) + (w0 + 4 * tw);
    *(float4*)&out[gbase] = float4{vals[0], vals[1], vals[2], vals[3]};
    // idx chunk is misaligned by 91 dwords; middle pair is 8B-aligned
    out_idx[gbase + 0] = idxf[0];
    *(float2*)&out_idx[gbase + 1] = float2{idxf[1], idxf[2]};
    out_idx[gbase + 3] = idxf[3];
  }
}

extern "C" void kernel_launch(void* const* d_in, const int* in_sizes, int n_in,
                              void* d_out, int out_size, void* d_ws, size_t ws_size,
                              hipStream_t stream) {
  const float* x    = (const float*)d_in[0];
  const float* co   = (const float*)d_in[1];
  const float* sfil = (const float*)d_in[2];
  float* out = (float*)d_out;
  uint32_t* wsu = (uint32_t*)d_ws;
  int nx = in_sizes[0];  // 8*16*256*256

  int n4 = nx / 4, ntail = nx - 4 * n4;

  float* out_co  = out + nx;
  float* out_sf  = out + nx + 64;
  float* out_idx = out + nx + 64 + 27;

  // zero the 32 spread atomic-max slots (one 128-B memset node)
  hipMemsetAsync(wsu + 64, 0, 128, stream);

  k_minmax<<<512, 256, 0, stream>>>(x, n4, ntail, co, sfil, wsu, out_co, out_sf);
  k_conv<<<4096, 256, 0, stream>>>(x, sfil, wsu, out, out_idx);
}